// Round 1
// baseline (346.504 us; speedup 1.0000x reference)
//
#include <hip/hip_runtime.h>

#define NEG_BIG -9.0e15f

// H[i][o] = sum_k X[i][k] * W[k][o]   (X:[1024,128], W:[128,128])
__global__ __launch_bounds__(128) void gemm_xw(const float* __restrict__ X,
                                               const float* __restrict__ W,
                                               float* __restrict__ H) {
  __shared__ float xrow[128];
  const int i = blockIdx.x;
  const int o = threadIdx.x;
  xrow[o] = X[(size_t)i * 128 + o];
  __syncthreads();
  float acc = 0.f;
#pragma unroll 16
  for (int k = 0; k < 128; ++k) acc = fmaf(xrow[k], W[(size_t)k * 128 + o], acc);
  H[(size_t)i * 128 + o] = acc;
}

#define ROWS 4
// Fused: e = relu(sum_f |h_j-h_i|*a_f) masked -> row softmax -> relu(att @ h)
__global__ __launch_bounds__(256) void gat_attn(const float* __restrict__ H,
                                                const int* __restrict__ adj,
                                                const float* __restrict__ a,
                                                float* __restrict__ Xout) {
  __shared__ float e_s[ROWS][1024];
  __shared__ float hi_s[ROWS][132];
  __shared__ float a_s[128];
  __shared__ float inv_s[ROWS];
  const int t = threadIdx.x;
  const int i0 = blockIdx.x * ROWS;

  if (t < 128) a_s[t] = a[t];
  {
    const int r = t >> 6;        // 0..3
    const int c = (t & 63) * 2;  // 0..126
    const float2 v = *reinterpret_cast<const float2*>(&H[(size_t)(i0 + r) * 128 + c]);
    hi_s[r][c] = v.x;
    hi_s[r][c + 1] = v.y;
  }
  __syncthreads();

  const int il = t >> 6;  // 0..3
  const int jt = t & 63;  // 0..63

  // ---- phase 1: e scores for 4 rows x 1024 cols ----
  for (int jc = 0; jc < 4; ++jc) {
    const int j0 = jc * 256 + jt * 4;
    float acc0 = 0.f, acc1 = 0.f, acc2 = 0.f, acc3 = 0.f;
    const float* __restrict__ hj0 = H + (size_t)(j0 + 0) * 128;
    const float* __restrict__ hj1 = H + (size_t)(j0 + 1) * 128;
    const float* __restrict__ hj2 = H + (size_t)(j0 + 2) * 128;
    const float* __restrict__ hj3 = H + (size_t)(j0 + 3) * 128;
#pragma unroll 4
    for (int f = 0; f < 128; f += 4) {
      const float4 hi4 = *reinterpret_cast<const float4*>(&hi_s[il][f]);
      const float4 a4 = *reinterpret_cast<const float4*>(&a_s[f]);
      const float4 h0 = *reinterpret_cast<const float4*>(hj0 + f);
      const float4 h1 = *reinterpret_cast<const float4*>(hj1 + f);
      const float4 h2 = *reinterpret_cast<const float4*>(hj2 + f);
      const float4 h3 = *reinterpret_cast<const float4*>(hj3 + f);
      acc0 = fmaf(fabsf(h0.x - hi4.x), a4.x, acc0);
      acc0 = fmaf(fabsf(h0.y - hi4.y), a4.y, acc0);
      acc0 = fmaf(fabsf(h0.z - hi4.z), a4.z, acc0);
      acc0 = fmaf(fabsf(h0.w - hi4.w), a4.w, acc0);
      acc1 = fmaf(fabsf(h1.x - hi4.x), a4.x, acc1);
      acc1 = fmaf(fabsf(h1.y - hi4.y), a4.y, acc1);
      acc1 = fmaf(fabsf(h1.z - hi4.z), a4.z, acc1);
      acc1 = fmaf(fabsf(h1.w - hi4.w), a4.w, acc1);
      acc2 = fmaf(fabsf(h2.x - hi4.x), a4.x, acc2);
      acc2 = fmaf(fabsf(h2.y - hi4.y), a4.y, acc2);
      acc2 = fmaf(fabsf(h2.z - hi4.z), a4.z, acc2);
      acc2 = fmaf(fabsf(h2.w - hi4.w), a4.w, acc2);
      acc3 = fmaf(fabsf(h3.x - hi4.x), a4.x, acc3);
      acc3 = fmaf(fabsf(h3.y - hi4.y), a4.y, acc3);
      acc3 = fmaf(fabsf(h3.z - hi4.z), a4.z, acc3);
      acc3 = fmaf(fabsf(h3.w - hi4.w), a4.w, acc3);
    }
    const int4 ad = *reinterpret_cast<const int4*>(&adj[(size_t)(i0 + il) * 1024 + j0]);
    float4 e;
    e.x = ad.x > 0 ? fmaxf(acc0, 0.f) : NEG_BIG;
    e.y = ad.y > 0 ? fmaxf(acc1, 0.f) : NEG_BIG;
    e.z = ad.z > 0 ? fmaxf(acc2, 0.f) : NEG_BIG;
    e.w = ad.w > 0 ? fmaxf(acc3, 0.f) : NEG_BIG;
    *reinterpret_cast<float4*>(&e_s[il][j0]) = e;
  }
  __syncthreads();

  // ---- phase 2: row softmax (64 threads per row) ----
  float m = NEG_BIG;
#pragma unroll
  for (int k = 0; k < 16; ++k) m = fmaxf(m, e_s[il][jt + 64 * k]);
#pragma unroll
  for (int off = 32; off > 0; off >>= 1) m = fmaxf(m, __shfl_xor(m, off));
  float s = 0.f;
#pragma unroll
  for (int k = 0; k < 16; ++k) {
    const float p = __expf(e_s[il][jt + 64 * k] - m);
    e_s[il][jt + 64 * k] = p;
    s += p;
  }
#pragma unroll
  for (int off = 32; off > 0; off >>= 1) s += __shfl_xor(s, off);
  if (jt == 0) inv_s[il] = 1.f / s;
  __syncthreads();

  // ---- phase 3: out = relu((p @ H) * inv) ----
  const int o4 = t >> 1;
  const int pil = o4 >> 5;
  const int f4 = (o4 & 31) * 4;
  const int jh = t & 1;
  float4 acc = {0.f, 0.f, 0.f, 0.f};
  const int jbeg = jh * 512;
#pragma unroll 4
  for (int j = jbeg; j < jbeg + 512; ++j) {
    const float p = e_s[pil][j];
    const float4 h4 = *reinterpret_cast<const float4*>(&H[(size_t)j * 128 + f4]);
    acc.x = fmaf(p, h4.x, acc.x);
    acc.y = fmaf(p, h4.y, acc.y);
    acc.z = fmaf(p, h4.z, acc.z);
    acc.w = fmaf(p, h4.w, acc.w);
  }
  acc.x += __shfl_xor(acc.x, 1);
  acc.y += __shfl_xor(acc.y, 1);
  acc.z += __shfl_xor(acc.z, 1);
  acc.w += __shfl_xor(acc.w, 1);
  if (jh == 0) {
    const float inv = inv_s[pil];
    float4 o;
    o.x = fmaxf(acc.x * inv, 0.f);
    o.y = fmaxf(acc.y * inv, 0.f);
    o.z = fmaxf(acc.z * inv, 0.f);
    o.w = fmaxf(acc.w * inv, 0.f);
    *reinterpret_cast<float4*>(&Xout[(size_t)(i0 + pil) * 128 + f4]) = o;
  }
}

// out[(i*1024+j)*16 + c] = sum_f |x_j[f]-x_i[f]| * Wfc[f][c] + bfc[c]
__global__ __launch_bounds__(256) void edge_fc(const float* __restrict__ X,
                                               const float* __restrict__ Wfc,
                                               const float* __restrict__ bfc,
                                               float* __restrict__ out) {
  __shared__ float xi_s[16][132];
  __shared__ float xj_s[16][132];
  const int t = threadIdx.x;
  const int bi = blockIdx.x >> 6;
  const int bj = blockIdx.x & 63;
  {
    const int r = t >> 4;
    const int c = (t & 15) * 8;
    const float4 v0 = *reinterpret_cast<const float4*>(&X[(size_t)(bi * 16 + r) * 128 + c]);
    const float4 v1 = *reinterpret_cast<const float4*>(&X[(size_t)(bi * 16 + r) * 128 + c + 4]);
    *reinterpret_cast<float4*>(&xi_s[r][c]) = v0;
    *reinterpret_cast<float4*>(&xi_s[r][c + 4]) = v1;
    const float4 u0 = *reinterpret_cast<const float4*>(&X[(size_t)(bj * 16 + r) * 128 + c]);
    const float4 u1 = *reinterpret_cast<const float4*>(&X[(size_t)(bj * 16 + r) * 128 + c + 4]);
    *reinterpret_cast<float4*>(&xj_s[r][c]) = u0;
    *reinterpret_cast<float4*>(&xj_s[r][c + 4]) = u1;
  }
  __syncthreads();
  const int il = t >> 4;
  const int jl = t & 15;
  float acc[16];
#pragma unroll
  for (int c = 0; c < 16; ++c) acc[c] = 0.f;
  const float4* __restrict__ W4 = reinterpret_cast<const float4*>(Wfc);
#pragma unroll 2
  for (int f = 0; f < 128; ++f) {
    const float dx = fabsf(xj_s[jl][f] - xi_s[il][f]);
    const float4 w0 = W4[f * 4 + 0];  // uniform -> s_load
    const float4 w1 = W4[f * 4 + 1];
    const float4 w2 = W4[f * 4 + 2];
    const float4 w3 = W4[f * 4 + 3];
    acc[0] = fmaf(dx, w0.x, acc[0]);
    acc[1] = fmaf(dx, w0.y, acc[1]);
    acc[2] = fmaf(dx, w0.z, acc[2]);
    acc[3] = fmaf(dx, w0.w, acc[3]);
    acc[4] = fmaf(dx, w1.x, acc[4]);
    acc[5] = fmaf(dx, w1.y, acc[5]);
    acc[6] = fmaf(dx, w1.z, acc[6]);
    acc[7] = fmaf(dx, w1.w, acc[7]);
    acc[8] = fmaf(dx, w2.x, acc[8]);
    acc[9] = fmaf(dx, w2.y, acc[9]);
    acc[10] = fmaf(dx, w2.z, acc[10]);
    acc[11] = fmaf(dx, w2.w, acc[11]);
    acc[12] = fmaf(dx, w3.x, acc[12]);
    acc[13] = fmaf(dx, w3.y, acc[13]);
    acc[14] = fmaf(dx, w3.z, acc[14]);
    acc[15] = fmaf(dx, w3.w, acc[15]);
  }
  const size_t pair = (size_t)(bi * 16 + il) * 1024 + (size_t)(bj * 16 + jl);
  float* o = out + pair * 16;
  const float4* __restrict__ b4 = reinterpret_cast<const float4*>(bfc);
#pragma unroll
  for (int c4 = 0; c4 < 4; ++c4) {
    const float4 bb = b4[c4];
    float4 v;
    v.x = acc[c4 * 4 + 0] + bb.x;
    v.y = acc[c4 * 4 + 1] + bb.y;
    v.z = acc[c4 * 4 + 2] + bb.z;
    v.w = acc[c4 * 4 + 3] + bb.w;
    *reinterpret_cast<float4*>(o + c4 * 4) = v;
  }
}

extern "C" void kernel_launch(void* const* d_in, const int* in_sizes, int n_in,
                              void* d_out, int out_size, void* d_ws, size_t ws_size,
                              hipStream_t stream) {
  const float* feat = (const float*)d_in[0];
  const int* adj = (const int*)d_in[1];
  const float* W1 = (const float*)d_in[2];
  const float* a1 = (const float*)d_in[3];
  const float* W2 = (const float*)d_in[4];
  const float* a2 = (const float*)d_in[5];
  const float* W3 = (const float*)d_in[6];
  const float* a3 = (const float*)d_in[7];
  const float* Wfc = (const float*)d_in[8];
  const float* bfc = (const float*)d_in[9];
  float* out = (float*)d_out;

  float* h = (float*)d_ws;         // 1024*128
  float* xA = h + 131072;          // 1024*128
  float* xB = xA + 131072;         // 1024*128

  gemm_xw<<<1024, 128, 0, stream>>>(feat, W1, h);
  gat_attn<<<256, 256, 0, stream>>>(h, adj, a1, xA);
  gemm_xw<<<1024, 128, 0, stream>>>(xA, W2, h);
  gat_attn<<<256, 256, 0, stream>>>(h, adj, a2, xB);
  gemm_xw<<<1024, 128, 0, stream>>>(xB, W3, h);
  gat_attn<<<256, 256, 0, stream>>>(h, adj, a3, xA);
  edge_fc<<<4096, 256, 0, stream>>>(xA, Wfc, bfc, out);
}

// Round 2
// 139.843 us; speedup vs baseline: 2.4778x; 2.4778x over previous
//
#include <hip/hip_runtime.h>

#define NEG_BIG -9.0e15f

// H^T[o][i] = sum_k X[i][k] * W[k][o]   (X:[1024,128], W:[128,128], HT:[128,1024])
__global__ __launch_bounds__(128) void gemm_xw_t(const float* __restrict__ X,
                                                 const float* __restrict__ W,
                                                 float* __restrict__ HT) {
  __shared__ float xrow[128];
  const int i = blockIdx.x;
  const int o = threadIdx.x;
  xrow[o] = X[(size_t)i * 128 + o];
  __syncthreads();
  float acc = 0.f;
#pragma unroll 16
  for (int k = 0; k < 128; ++k) acc = fmaf(xrow[k], W[(size_t)k * 128 + o], acc);
  HT[(size_t)o * 1024 + i] = acc;
}

#define ABSFMA4(acc, hv, ha)                        \
  acc.x = fmaf(fabsf(hv.x - ha.x), ha.y, acc.x);    \
  acc.y = fmaf(fabsf(hv.y - ha.x), ha.y, acc.y);    \
  acc.z = fmaf(fabsf(hv.z - ha.x), ha.y, acc.z);    \
  acc.w = fmaf(fabsf(hv.w - ha.x), ha.y, acc.w);

#define DOT4(acc, hv, p) \
  acc = fmaf(hv.x, p.x, fmaf(hv.y, p.y, fmaf(hv.z, p.z, fmaf(hv.w, p.w, acc))));

// Fused GAT layer, 4 rows per block, 1024 threads, HT input (transposed).
__global__ __launch_bounds__(1024, 4) void gat_attn(const float* __restrict__ HT,
                                                    const int* __restrict__ adj,
                                                    const float* __restrict__ a,
                                                    float* __restrict__ Xout) {
  __shared__ float ep2[2][4][1024];   // 32 KB: f-half partials [fh][il][j]
  __shared__ float e_s[4][1024];      // 16 KB: p (post-softmax weights)
  __shared__ float2 ha_s[4][128];     // (h_i[f], a[f]) per row
  __shared__ float redm[4][4];
  __shared__ float redsum[4][4];
  __shared__ float inv_s[4];

  const int t = threadIdx.x;
  const int i0 = blockIdx.x * 4;
  const float4* __restrict__ HT4 = reinterpret_cast<const float4*>(HT);

  if (t < 512) {
    const int pil = t >> 7;
    const int f = t & 127;
    ha_s[pil][f] = make_float2(HT[(size_t)f * 1024 + i0 + pil], a[f]);
  }
  __syncthreads();

  // ---- phase 1: e[il][j] = sum_f |HT[f][j] - h_i[f]| * a[f], two f-passes ----
  const int ih = t >> 9;        // 0..1 : which pair of rows
  const int fh = (t >> 8) & 1;  // 0..1 : f half within pass
  const int jt = t & 255;       // j-group: 4 j, float4 index jt
  const int il = t >> 8;        // reduce-role row
  const int j0 = (t & 255) * 4;

  float4 esum = {0.f, 0.f, 0.f, 0.f};
#pragma unroll
  for (int pass = 0; pass < 2; ++pass) {
    const int fb = pass * 64 + fh * 32;
    float4 aA = {0.f, 0.f, 0.f, 0.f};
    float4 aB = {0.f, 0.f, 0.f, 0.f};
#pragma unroll 4
    for (int ff = 0; ff < 32; ++ff) {
      const int f = fb + ff;
      const float4 hv = HT4[f * 256 + jt];
      const float2 hA = ha_s[ih * 2][f];
      const float2 hB = ha_s[ih * 2 + 1][f];
      ABSFMA4(aA, hv, hA);
      ABSFMA4(aB, hv, hB);
    }
    *reinterpret_cast<float4*>(&ep2[fh][ih * 2][jt * 4]) = aA;
    *reinterpret_cast<float4*>(&ep2[fh][ih * 2 + 1][jt * 4]) = aB;
    __syncthreads();
    {
      const float4 s0 = *reinterpret_cast<const float4*>(&ep2[0][il][j0]);
      const float4 s1 = *reinterpret_cast<const float4*>(&ep2[1][il][j0]);
      esum.x += s0.x + s1.x;
      esum.y += s0.y + s1.y;
      esum.z += s0.z + s1.z;
      esum.w += s0.w + s1.w;
    }
    __syncthreads();  // safe to overwrite ep2 next pass
  }

  // ---- mask + relu ----
  float4 e;
  {
    const int4 ad = *reinterpret_cast<const int4*>(&adj[(size_t)(i0 + il) * 1024 + j0]);
    e.x = ad.x > 0 ? fmaxf(esum.x, 0.f) : NEG_BIG;
    e.y = ad.y > 0 ? fmaxf(esum.y, 0.f) : NEG_BIG;
    e.z = ad.z > 0 ? fmaxf(esum.z, 0.f) : NEG_BIG;
    e.w = ad.w > 0 ? fmaxf(esum.w, 0.f) : NEG_BIG;
  }

  // ---- softmax over j (256 threads = 4 waves per row) ----
  const int wq = (t >> 6) & 3;
  float m = fmaxf(fmaxf(e.x, e.y), fmaxf(e.z, e.w));
#pragma unroll
  for (int off = 32; off > 0; off >>= 1) m = fmaxf(m, __shfl_xor(m, off));
  if ((t & 63) == 0) redm[il][wq] = m;
  __syncthreads();
  m = fmaxf(fmaxf(redm[il][0], redm[il][1]), fmaxf(redm[il][2], redm[il][3]));
  float4 p;
  p.x = __expf(e.x - m);
  p.y = __expf(e.y - m);
  p.z = __expf(e.z - m);
  p.w = __expf(e.w - m);
  *reinterpret_cast<float4*>(&e_s[il][j0]) = p;
  float s = p.x + p.y + p.z + p.w;
#pragma unroll
  for (int off = 32; off > 0; off >>= 1) s += __shfl_xor(s, off);
  if ((t & 63) == 0) redsum[il][wq] = s;
  __syncthreads();
  if (t < 4) {
    const float ss = redsum[t][0] + redsum[t][1] + redsum[t][2] + redsum[t][3];
    inv_s[t] = 1.f / ss;
  }
  __syncthreads();

  // ---- phase 3: out[il][f] = relu(inv[il] * sum_j p[il][j] * HT[f][j]) ----
  // wave w owns f = w*8 .. w*8+7 for all 4 rows; lanes spread over j.
  const int w = t >> 6;
  const int l = t & 63;
  const int f0 = w * 8;
  float acc[8][4];
#pragma unroll
  for (int ff = 0; ff < 8; ++ff)
#pragma unroll
    for (int r = 0; r < 4; ++r) acc[ff][r] = 0.f;

#pragma unroll
  for (int jb = 0; jb < 4; ++jb) {
    const int j4 = jb * 64 + l;
    const float4 p0 = *reinterpret_cast<const float4*>(&e_s[0][j4 * 4]);
    const float4 p1 = *reinterpret_cast<const float4*>(&e_s[1][j4 * 4]);
    const float4 p2 = *reinterpret_cast<const float4*>(&e_s[2][j4 * 4]);
    const float4 p3 = *reinterpret_cast<const float4*>(&e_s[3][j4 * 4]);
#pragma unroll
    for (int ff = 0; ff < 8; ++ff) {
      const float4 hv = HT4[(f0 + ff) * 256 + j4];
      DOT4(acc[ff][0], hv, p0);
      DOT4(acc[ff][1], hv, p1);
      DOT4(acc[ff][2], hv, p2);
      DOT4(acc[ff][3], hv, p3);
    }
  }

  // merge-tree reduction: 32 outputs across 64 lanes -> lane (l&31) holds output
  float v[32];
#pragma unroll
  for (int ff = 0; ff < 8; ++ff)
#pragma unroll
    for (int r = 0; r < 4; ++r) v[ff * 4 + r] = acc[ff][r];

#pragma unroll
  for (int step = 0; step < 5; ++step) {
    const int s2 = 1 << step;
    const bool hi = (l & s2) != 0;
#pragma unroll
    for (int k = 0; k < (32 >> (step + 1)); ++k) {
      const float x = v[2 * k];
      const float y = v[2 * k + 1];
      float tt = hi ? x : y;
      tt = __shfl_xor(tt, s2);
      v[k] = (hi ? y : x) + tt;
    }
  }
  float r = v[0] + __shfl_xor(v[0], 32);

  if (l < 32) {
    const int oidx = l & 31;
    const int ff = oidx >> 2;
    const int orow = oidx & 3;
    const float o = fmaxf(r * inv_s[orow], 0.f);
    Xout[(size_t)(i0 + orow) * 128 + f0 + ff] = o;
  }
}

// out[(i*1024+j)*16 + c] = sum_f |x_j[f]-x_i[f]| * Wfc[f][c] + bfc[c]
__global__ __launch_bounds__(256) void edge_fc(const float* __restrict__ X,
                                               const float* __restrict__ Wfc,
                                               const float* __restrict__ bfc,
                                               float* __restrict__ out) {
  __shared__ float xi_s[16][132];
  __shared__ float xj_s[16][132];
  const int t = threadIdx.x;
  const int bi = blockIdx.x >> 6;
  const int bj = blockIdx.x & 63;
  {
    const int r = t >> 4;
    const int c = (t & 15) * 8;
    const float4 v0 = *reinterpret_cast<const float4*>(&X[(size_t)(bi * 16 + r) * 128 + c]);
    const float4 v1 = *reinterpret_cast<const float4*>(&X[(size_t)(bi * 16 + r) * 128 + c + 4]);
    *reinterpret_cast<float4*>(&xi_s[r][c]) = v0;
    *reinterpret_cast<float4*>(&xi_s[r][c + 4]) = v1;
    const float4 u0 = *reinterpret_cast<const float4*>(&X[(size_t)(bj * 16 + r) * 128 + c]);
    const float4 u1 = *reinterpret_cast<const float4*>(&X[(size_t)(bj * 16 + r) * 128 + c + 4]);
    *reinterpret_cast<float4*>(&xj_s[r][c]) = u0;
    *reinterpret_cast<float4*>(&xj_s[r][c + 4]) = u1;
  }
  __syncthreads();
  const int il = t >> 4;
  const int jl = t & 15;
  float acc[16];
#pragma unroll
  for (int c = 0; c < 16; ++c) acc[c] = 0.f;
  const float4* __restrict__ W4 = reinterpret_cast<const float4*>(Wfc);
#pragma unroll 2
  for (int f = 0; f < 128; ++f) {
    const float dx = fabsf(xj_s[jl][f] - xi_s[il][f]);
    const float4 w0 = W4[f * 4 + 0];
    const float4 w1 = W4[f * 4 + 1];
    const float4 w2 = W4[f * 4 + 2];
    const float4 w3 = W4[f * 4 + 3];
    acc[0] = fmaf(dx, w0.x, acc[0]);
    acc[1] = fmaf(dx, w0.y, acc[1]);
    acc[2] = fmaf(dx, w0.z, acc[2]);
    acc[3] = fmaf(dx, w0.w, acc[3]);
    acc[4] = fmaf(dx, w1.x, acc[4]);
    acc[5] = fmaf(dx, w1.y, acc[5]);
    acc[6] = fmaf(dx, w1.z, acc[6]);
    acc[7] = fmaf(dx, w1.w, acc[7]);
    acc[8] = fmaf(dx, w2.x, acc[8]);
    acc[9] = fmaf(dx, w2.y, acc[9]);
    acc[10] = fmaf(dx, w2.z, acc[10]);
    acc[11] = fmaf(dx, w2.w, acc[11]);
    acc[12] = fmaf(dx, w3.x, acc[12]);
    acc[13] = fmaf(dx, w3.y, acc[13]);
    acc[14] = fmaf(dx, w3.z, acc[14]);
    acc[15] = fmaf(dx, w3.w, acc[15]);
  }
  const size_t pair = (size_t)(bi * 16 + il) * 1024 + (size_t)(bj * 16 + jl);
  float* o = out + pair * 16;
  const float4* __restrict__ b4 = reinterpret_cast<const float4*>(bfc);
#pragma unroll
  for (int c4 = 0; c4 < 4; ++c4) {
    const float4 bb = b4[c4];
    float4 v;
    v.x = acc[c4 * 4 + 0] + bb.x;
    v.y = acc[c4 * 4 + 1] + bb.y;
    v.z = acc[c4 * 4 + 2] + bb.z;
    v.w = acc[c4 * 4 + 3] + bb.w;
    *reinterpret_cast<float4*>(o + c4 * 4) = v;
  }
}

extern "C" void kernel_launch(void* const* d_in, const int* in_sizes, int n_in,
                              void* d_out, int out_size, void* d_ws, size_t ws_size,
                              hipStream_t stream) {
  const float* feat = (const float*)d_in[0];
  const int* adj = (const int*)d_in[1];
  const float* W1 = (const float*)d_in[2];
  const float* a1 = (const float*)d_in[3];
  const float* W2 = (const float*)d_in[4];
  const float* a2 = (const float*)d_in[5];
  const float* W3 = (const float*)d_in[6];
  const float* a3 = (const float*)d_in[7];
  const float* Wfc = (const float*)d_in[8];
  const float* bfc = (const float*)d_in[9];
  float* out = (float*)d_out;

  float* ht = (float*)d_ws;        // 1024*128 (transposed H)
  float* xA = ht + 131072;         // 1024*128
  float* xB = xA + 131072;         // 1024*128

  gemm_xw_t<<<1024, 128, 0, stream>>>(feat, W1, ht);
  gat_attn<<<256, 1024, 0, stream>>>(ht, adj, a1, xA);
  gemm_xw_t<<<1024, 128, 0, stream>>>(xA, W2, ht);
  gat_attn<<<256, 1024, 0, stream>>>(ht, adj, a2, xB);
  gemm_xw_t<<<1024, 128, 0, stream>>>(xB, W3, ht);
  gat_attn<<<256, 1024, 0, stream>>>(ht, adj, a3, xA);
  edge_fc<<<4096, 256, 0, stream>>>(xA, Wfc, bfc, out);
}

// Round 3
// 107.859 us; speedup vs baseline: 3.2126x; 1.2965x over previous
//
#include <hip/hip_runtime.h>
#include <math.h>

#define NEG_BIG -9.0e15f

typedef __attribute__((ext_vector_type(4))) float f32x4;
typedef __attribute__((ext_vector_type(8))) short bf16x8;

// H^T[o][i] = sum_k X[i][k] * W[k][o]   (X:[1024,128], W:[128,128], HT:[128,1024])
__global__ __launch_bounds__(128) void gemm_xw_t(const float* __restrict__ X,
                                                 const float* __restrict__ W,
                                                 float* __restrict__ HT) {
  __shared__ float xrow[128];
  const int i = blockIdx.x;
  const int o = threadIdx.x;
  xrow[o] = X[(size_t)i * 128 + o];
  __syncthreads();
  float acc = 0.f;
#pragma unroll 16
  for (int k = 0; k < 128; ++k) acc = fmaf(xrow[k], W[(size_t)k * 128 + o], acc);
  HT[(size_t)o * 1024 + i] = acc;
}

#define ABSFMA4(acc, hv, ha)                        \
  acc.x = fmaf(fabsf(hv.x - ha.x), ha.y, acc.x);    \
  acc.y = fmaf(fabsf(hv.y - ha.x), ha.y, acc.y);    \
  acc.z = fmaf(fabsf(hv.z - ha.x), ha.y, acc.z);    \
  acc.w = fmaf(fabsf(hv.w - ha.x), ha.y, acc.w);

#define DOT4(acc, hv, p) \
  acc = fmaf(hv.x, p.x, fmaf(hv.y, p.y, fmaf(hv.z, p.z, fmaf(hv.w, p.w, acc))));

// Fused GAT layer, 4 rows per block, 1024 threads, HT input (transposed).
__global__ __launch_bounds__(1024, 4) void gat_attn(const float* __restrict__ HT,
                                                    const int* __restrict__ adj,
                                                    const float* __restrict__ a,
                                                    float* __restrict__ Xout) {
  __shared__ float ep2[2][4][1024];   // 32 KB: f-half partials [fh][il][j]
  __shared__ float e_s[4][1024];      // 16 KB: p (post-softmax weights)
  __shared__ float2 ha_s[4][128];     // (h_i[f], a[f]) per row
  __shared__ float redm[4][4];
  __shared__ float redsum[4][4];
  __shared__ float inv_s[4];

  const int t = threadIdx.x;
  const int i0 = blockIdx.x * 4;
  const float4* __restrict__ HT4 = reinterpret_cast<const float4*>(HT);

  if (t < 512) {
    const int pil = t >> 7;
    const int f = t & 127;
    ha_s[pil][f] = make_float2(HT[(size_t)f * 1024 + i0 + pil], a[f]);
  }
  __syncthreads();

  const int ih = t >> 9;        // 0..1 : which pair of rows
  const int fh = (t >> 8) & 1;  // 0..1 : f half within pass
  const int jt = t & 255;       // j-group: 4 j, float4 index jt
  const int il = t >> 8;        // reduce-role row
  const int j0 = (t & 255) * 4;

  float4 esum = {0.f, 0.f, 0.f, 0.f};
#pragma unroll
  for (int pass = 0; pass < 2; ++pass) {
    const int fb = pass * 64 + fh * 32;
    float4 aA = {0.f, 0.f, 0.f, 0.f};
    float4 aB = {0.f, 0.f, 0.f, 0.f};
#pragma unroll 4
    for (int ff = 0; ff < 32; ++ff) {
      const int f = fb + ff;
      const float4 hv = HT4[f * 256 + jt];
      const float2 hA = ha_s[ih * 2][f];
      const float2 hB = ha_s[ih * 2 + 1][f];
      ABSFMA4(aA, hv, hA);
      ABSFMA4(aB, hv, hB);
    }
    *reinterpret_cast<float4*>(&ep2[fh][ih * 2][jt * 4]) = aA;
    *reinterpret_cast<float4*>(&ep2[fh][ih * 2 + 1][jt * 4]) = aB;
    __syncthreads();
    {
      const float4 s0 = *reinterpret_cast<const float4*>(&ep2[0][il][j0]);
      const float4 s1 = *reinterpret_cast<const float4*>(&ep2[1][il][j0]);
      esum.x += s0.x + s1.x;
      esum.y += s0.y + s1.y;
      esum.z += s0.z + s1.z;
      esum.w += s0.w + s1.w;
    }
    __syncthreads();
  }

  float4 e;
  {
    const int4 ad = *reinterpret_cast<const int4*>(&adj[(size_t)(i0 + il) * 1024 + j0]);
    e.x = ad.x > 0 ? fmaxf(esum.x, 0.f) : NEG_BIG;
    e.y = ad.y > 0 ? fmaxf(esum.y, 0.f) : NEG_BIG;
    e.z = ad.z > 0 ? fmaxf(esum.z, 0.f) : NEG_BIG;
    e.w = ad.w > 0 ? fmaxf(esum.w, 0.f) : NEG_BIG;
  }

  const int wq = (t >> 6) & 3;
  float m = fmaxf(fmaxf(e.x, e.y), fmaxf(e.z, e.w));
#pragma unroll
  for (int off = 32; off > 0; off >>= 1) m = fmaxf(m, __shfl_xor(m, off));
  if ((t & 63) == 0) redm[il][wq] = m;
  __syncthreads();
  m = fmaxf(fmaxf(redm[il][0], redm[il][1]), fmaxf(redm[il][2], redm[il][3]));
  float4 p;
  p.x = __expf(e.x - m);
  p.y = __expf(e.y - m);
  p.z = __expf(e.z - m);
  p.w = __expf(e.w - m);
  *reinterpret_cast<float4*>(&e_s[il][j0]) = p;
  float s = p.x + p.y + p.z + p.w;
#pragma unroll
  for (int off = 32; off > 0; off >>= 1) s += __shfl_xor(s, off);
  if ((t & 63) == 0) redsum[il][wq] = s;
  __syncthreads();
  if (t < 4) {
    const float ss = redsum[t][0] + redsum[t][1] + redsum[t][2] + redsum[t][3];
    inv_s[t] = 1.f / ss;
  }
  __syncthreads();

  // ---- phase 3: out[il][f] = relu(inv[il] * sum_j p[il][j] * HT[f][j]) ----
  const int w = t >> 6;
  const int l = t & 63;
  const int f0 = w * 8;
  float acc[8][4];
#pragma unroll
  for (int ff = 0; ff < 8; ++ff)
#pragma unroll
    for (int r = 0; r < 4; ++r) acc[ff][r] = 0.f;

#pragma unroll
  for (int jb = 0; jb < 4; ++jb) {
    const int j4 = jb * 64 + l;
    const float4 p0 = *reinterpret_cast<const float4*>(&e_s[0][j4 * 4]);
    const float4 p1 = *reinterpret_cast<const float4*>(&e_s[1][j4 * 4]);
    const float4 p2 = *reinterpret_cast<const float4*>(&e_s[2][j4 * 4]);
    const float4 p3 = *reinterpret_cast<const float4*>(&e_s[3][j4 * 4]);
#pragma unroll
    for (int ff = 0; ff < 8; ++ff) {
      const float4 hv = HT4[(f0 + ff) * 256 + j4];
      DOT4(acc[ff][0], hv, p0);
      DOT4(acc[ff][1], hv, p1);
      DOT4(acc[ff][2], hv, p2);
      DOT4(acc[ff][3], hv, p3);
    }
  }

  float v[32];
#pragma unroll
  for (int ff = 0; ff < 8; ++ff)
#pragma unroll
    for (int r = 0; r < 4; ++r) v[ff * 4 + r] = acc[ff][r];

#pragma unroll
  for (int step = 0; step < 5; ++step) {
    const int s2 = 1 << step;
    const bool hi = (l & s2) != 0;
#pragma unroll
    for (int k = 0; k < (32 >> (step + 1)); ++k) {
      const float x = v[2 * k];
      const float y = v[2 * k + 1];
      float tt = hi ? x : y;
      tt = __shfl_xor(tt, s2);
      v[k] = (hi ? y : x) + tt;
    }
  }
  float r = v[0] + __shfl_xor(v[0], 32);

  if (l < 32) {
    const int oidx = l & 31;
    const int ff = oidx >> 2;
    const int orow = oidx & 3;
    const float o = fmaxf(r * inv_s[orow], 0.f);
    Xout[(size_t)(i0 + orow) * 128 + f0 + ff] = o;
  }
}

// Symmetric EdgeGCN head via bf16-split MFMA.
// out[(i*1024+j)*16+c] = sum_f |x_j[f]-x_i[f]| * Wfc[f][c] + bfc[c]; out(i,j)==out(j,i).
// Tile 32i x 32j pairs per block, only ib<=jb (528 blocks), mirror-write.
__global__ __launch_bounds__(256) void edge_fc_mfma(const float* __restrict__ X,
                                                    const float* __restrict__ Wfc,
                                                    const float* __restrict__ bfc,
                                                    float* __restrict__ out) {
  __shared__ float xi_s[32][132];
  __shared__ float xj_s[32][132];

  const int t = threadIdx.x;
  const int bid = blockIdx.x;
  int jb = (int)((sqrtf(8.0f * (float)bid + 1.0f) - 1.0f) * 0.5f);
  int ib = bid - jb * (jb + 1) / 2;
  if (ib > jb) { jb++; ib = bid - jb * (jb + 1) / 2; }
  if (ib < 0) { jb--; ib = bid - jb * (jb + 1) / 2; }

  // stage x tiles
  {
    const int r = t >> 3;
    const int c0 = (t & 7) * 16;
    const float4* gi = reinterpret_cast<const float4*>(X + (size_t)(ib * 32 + r) * 128 + c0);
    const float4* gj = reinterpret_cast<const float4*>(X + (size_t)(jb * 32 + r) * 128 + c0);
#pragma unroll
    for (int k = 0; k < 4; ++k) {
      *reinterpret_cast<float4*>(&xi_s[r][c0 + k * 4]) = gi[k];
      *reinterpret_cast<float4*>(&xj_s[r][c0 + k * 4]) = gj[k];
    }
  }

  const int w = t >> 6;      // wave 0..3
  const int lane = t & 63;
  const int col = lane & 15;  // output channel / A row-sel
  const int kg = lane >> 4;   // k-group 0..3

  // B fragments (Wfc split), consistent k convention: k = c*32 + kg*8 + j
  bf16x8 bhi[4], blo[4];
#pragma unroll
  for (int c = 0; c < 4; ++c) {
    bf16x8 bh, bl;
#pragma unroll
    for (int j = 0; j < 8; ++j) {
      const float wv = Wfc[(c * 32 + kg * 8 + j) * 16 + col];
      const unsigned u = __builtin_bit_cast(unsigned, wv);
      const unsigned h = u & 0xffff0000u;
      const float lof = wv - __builtin_bit_cast(float, h);
      bh[j] = (short)(h >> 16);
      bl[j] = (short)(__builtin_bit_cast(unsigned, lof) >> 16);
    }
    bhi[c] = bh;
    blo[c] = bl;
  }
  const float bb = bfc[col];

  __syncthreads();

  // preload this wave's xj slice into registers: rows j0..j0+15, k-slice per lane
  const int j0 = (w & 1) * 16;
  const int ih = w >> 1;
  float xjr[4][8];
#pragma unroll
  for (int c = 0; c < 4; ++c) {
    const float4 v0 = *reinterpret_cast<const float4*>(&xj_s[j0 + col][c * 32 + kg * 8]);
    const float4 v1 = *reinterpret_cast<const float4*>(&xj_s[j0 + col][c * 32 + kg * 8 + 4]);
    xjr[c][0] = v0.x; xjr[c][1] = v0.y; xjr[c][2] = v0.z; xjr[c][3] = v0.w;
    xjr[c][4] = v1.x; xjr[c][5] = v1.y; xjr[c][6] = v1.z; xjr[c][7] = v1.w;
  }

  const int gjbase = jb * 32 + j0 + kg * 4;
  const bool mirror = (ib != jb);

  for (int i = 0; i < 16; ++i) {
    const int li = ih * 16 + i;
    f32x4 acc = {bb, bb, bb, bb};
#pragma unroll
    for (int c = 0; c < 4; ++c) {
      const float4 v0 = *reinterpret_cast<const float4*>(&xi_s[li][c * 32 + kg * 8]);
      const float4 v1 = *reinterpret_cast<const float4*>(&xi_s[li][c * 32 + kg * 8 + 4]);
      float xiv[8];
      xiv[0] = v0.x; xiv[1] = v0.y; xiv[2] = v0.z; xiv[3] = v0.w;
      xiv[4] = v1.x; xiv[5] = v1.y; xiv[6] = v1.z; xiv[7] = v1.w;
      bf16x8 ah, al;
#pragma unroll
      for (int j = 0; j < 8; ++j) {
        const float d = fabsf(xjr[c][j] - xiv[j]);
        const unsigned u = __builtin_bit_cast(unsigned, d);
        const unsigned h = u & 0xffff0000u;
        const float lof = d - __builtin_bit_cast(float, h);
        ah[j] = (short)(h >> 16);
        al[j] = (short)(__builtin_bit_cast(unsigned, lof) >> 16);
      }
      acc = __builtin_amdgcn_mfma_f32_16x16x32_bf16(ah, bhi[c], acc, 0, 0, 0);
      acc = __builtin_amdgcn_mfma_f32_16x16x32_bf16(ah, blo[c], acc, 0, 0, 0);
      acc = __builtin_amdgcn_mfma_f32_16x16x32_bf16(al, bhi[c], acc, 0, 0, 0);
    }
    const int gi = ib * 32 + li;
#pragma unroll
    for (int r = 0; r < 4; ++r) {
      out[((size_t)gi * 1024 + gjbase + r) * 16 + col] = acc[r];
    }
    if (mirror) {
#pragma unroll
      for (int r = 0; r < 4; ++r) {
        out[((size_t)(gjbase + r) * 1024 + gi) * 16 + col] = acc[r];
      }
    }
  }
}

extern "C" void kernel_launch(void* const* d_in, const int* in_sizes, int n_in,
                              void* d_out, int out_size, void* d_ws, size_t ws_size,
                              hipStream_t stream) {
  const float* feat = (const float*)d_in[0];
  const int* adj = (const int*)d_in[1];
  const float* W1 = (const float*)d_in[2];
  const float* a1 = (const float*)d_in[3];
  const float* W2 = (const float*)d_in[4];
  const float* a2 = (const float*)d_in[5];
  const float* W3 = (const float*)d_in[6];
  const float* a3 = (const float*)d_in[7];
  const float* Wfc = (const float*)d_in[8];
  const float* bfc = (const float*)d_in[9];
  float* out = (float*)d_out;

  float* ht = (float*)d_ws;        // 1024*128 (transposed H)
  float* xA = ht + 131072;         // 1024*128
  float* xB = xA + 131072;         // 1024*128

  gemm_xw_t<<<1024, 128, 0, stream>>>(feat, W1, ht);
  gat_attn<<<256, 1024, 0, stream>>>(ht, adj, a1, xA);
  gemm_xw_t<<<1024, 128, 0, stream>>>(xA, W2, ht);
  gat_attn<<<256, 1024, 0, stream>>>(ht, adj, a2, xB);
  gemm_xw_t<<<1024, 128, 0, stream>>>(xB, W3, ht);
  gat_attn<<<256, 1024, 0, stream>>>(ht, adj, a3, xA);
  edge_fc_mfma<<<528, 256, 0, stream>>>(xA, Wfc, bfc, out);
}